// Round 1
// baseline (838.541 us; speedup 1.0000x reference)
//
#include <hip/hip_runtime.h>
#include <hip/hip_bf16.h>
#include <stdint.h>

#define DIM 256
#define NG 8192
#define KDIM 512      // 2*DIM (concat [readout | h])
#define GDIM 1024     // 4*DIM gates
#define N_ITERS 6
#define CHUNK 32

#define BM 128
#define BN 128
#define BK 64

typedef __hip_bfloat16 bf16;
typedef __attribute__((ext_vector_type(8))) short bf16x8;
typedef __attribute__((ext_vector_type(4))) float f32x4;

// ---------------- async global->LDS (16B per lane, wave-uniform LDS base) --------------
__device__ __forceinline__ void async16(void* lds, const void* g) {
    __builtin_amdgcn_global_load_lds((const __attribute__((address_space(1))) void*)g,
                                     (__attribute__((address_space(3))) void*)lds, 16, 0, 0);
}

__device__ __forceinline__ float fast_sigmoid(float v) {
    return 1.0f / (1.0f + __expf(-v));
}
__device__ __forceinline__ float fast_tanh(float v) {
    // tanh(x) = 1 - 2/(exp(2x)+1); saturates correctly for large |x| with __expf
    float e = __expf(2.0f * v);
    return (e - 1.0f) / (e + 1.0f);
}

// ---------------- CSR offsets from sorted batch ----------------
__global__ void k_offsets(const int* __restrict__ batch, int* __restrict__ offs, int n_nodes) {
    int v = blockIdx.x * blockDim.x + threadIdx.x;
    if (v >= n_nodes) return;
    int b = batch[v];
    int bp = (v == 0) ? -1 : batch[v - 1];
    for (int g = bp + 1; g <= b; ++g) offs[g] = v;
    if (v == n_nodes - 1) {
        for (int g = b + 1; g <= NG; ++g) offs[g] = n_nodes;
    }
}

// ---------------- W concat + cast to bf16, bias sum ----------------
__global__ void k_prep_w(const float* __restrict__ Wih, const float* __restrict__ Whh,
                         const float* __restrict__ bih, const float* __restrict__ bhh,
                         bf16* __restrict__ Wcat, float* __restrict__ bsum) {
    int idx = blockIdx.x * blockDim.x + threadIdx.x;
    if (idx < GDIM * KDIM) {
        int j = idx >> 9;       // / KDIM
        int k = idx & (KDIM - 1);
        float v = (k < DIM) ? Wih[j * DIM + k] : Whh[j * DIM + (k - DIM)];
        Wcat[idx] = __float2bfloat16(v);
    }
    if (idx < GDIM) bsum[idx] = bih[idx] + bhh[idx];
}

// ---------------- zero-init h, c, Acat ----------------
__global__ void k_zero(float* __restrict__ h, float* __restrict__ c, bf16* __restrict__ Acat) {
    int i = blockIdx.x * blockDim.x + threadIdx.x;
    if (i < NG * DIM) { h[i] = 0.0f; c[i] = 0.0f; }
    if (i < NG * KDIM) Acat[i] = __float2bfloat16(0.0f);
}

// ---------------- fused attention readout: one block per graph ----------------
// scores = <x_v, h_g>; online softmax (max clamped at 0); readout = sum w_v x_v.
// x rows staged in LDS so x is read from global exactly ONCE per iteration.
__global__ __launch_bounds__(256) void k_att(const float* __restrict__ x,
                                             const float* __restrict__ h,
                                             const int* __restrict__ offs,
                                             float* __restrict__ readout,
                                             bf16* __restrict__ Acat) {
    const int g = blockIdx.x;
    const int tid = threadIdx.x;
    const int wave = tid >> 6, lane = tid & 63;

    __shared__ float xs[CHUNK][DIM];   // 32 KB
    __shared__ float sc[CHUNK];
    __shared__ float esh[CHUNK];
    __shared__ float hs[DIM];

    hs[tid] = h[(size_t)g * DIM + tid];
    __syncthreads();
    const float4 hreg = *(const float4*)&hs[lane * 4];

    const int start = offs[g], end = offs[g + 1];
    float racc = 0.0f;   // this thread owns dim `tid`
    float m = 0.0f;      // running max, init 0 == the max(seg_max, 0) clamp
    float s = 0.0f;      // running sum of exp

    for (int base = start; base < end; base += CHUNK) {
        const int cnt = min(CHUNK, end - base);
        // Phase A: each wave handles nodes round-robin; stage x row in LDS + dot with h
        for (int i = wave; i < cnt; i += 4) {
            const float4 xv = ((const float4*)(x + (size_t)(base + i) * DIM))[lane];
            ((float4*)xs[i])[lane] = xv;
            float d = xv.x * hreg.x + xv.y * hreg.y + xv.z * hreg.z + xv.w * hreg.w;
            #pragma unroll
            for (int off = 32; off > 0; off >>= 1) d += __shfl_xor(d, off);
            if (lane == 0) sc[i] = d;
        }
        __syncthreads();
        // Phase B: block-uniform online-softmax update
        float cmax = m;
        for (int i = 0; i < cnt; ++i) cmax = fmaxf(cmax, sc[i]);
        const float alpha = __expf(m - cmax);
        racc *= alpha;
        s *= alpha;
        if (tid < cnt) esh[tid] = __expf(sc[tid] - cmax);
        m = cmax;
        __syncthreads();
        // Phase C: weighted accumulation; thread tid owns dim tid (stride-1 LDS = free 2-way)
        for (int i = 0; i < cnt; ++i) {
            const float e = esh[i];
            s += e;
            racc += e * xs[i][tid];
        }
        __syncthreads();
    }

    const float out = racc / (s + 1e-8f);
    readout[(size_t)g * DIM + tid] = out;
    Acat[(size_t)g * KDIM + tid] = __float2bfloat16(out);
}

// ---------------- GEMM: gates = Acat(8192x512, bf16) @ Wcat(1024x512, bf16)^T + bsum ----
// m97-style: 128x128 tile, BK=64, 4 waves (2x2), each wave 64x64 via 4x4 MFMA 16x16x32.
__global__ __launch_bounds__(256) void k_gemm(const bf16* __restrict__ A,
                                              const bf16* __restrict__ B,
                                              const float* __restrict__ bsum,
                                              float* __restrict__ gates) {
    __shared__ bf16 As[BM * BK];   // row-major [m][k], 16 KB (no padding: global_load_lds)
    __shared__ bf16 Bs[BN * BK];

    const int tid = threadIdx.x;
    const int wave = tid >> 6, lane = tid & 63;
    const int m0 = blockIdx.x * BM;
    const int n0 = blockIdx.y * BN;
    const int wr = wave >> 1, wc = wave & 1;

    f32x4 acc[4][4] = {};

    const int row_in_grp = lane >> 3;  // 0..7
    const int chunk = lane & 7;        // 16B chunk within a 128B row

    for (int k0 = 0; k0 < KDIM; k0 += BK) {
        #pragma unroll
        for (int i = 0; i < 4; ++i) {
            const int row = wave * 32 + i * 8 + row_in_grp;
            async16(&As[(wave * 32 + i * 8) * BK],
                    A + (size_t)(m0 + row) * KDIM + k0 + chunk * 8);
        }
        #pragma unroll
        for (int i = 0; i < 4; ++i) {
            const int row = wave * 32 + i * 8 + row_in_grp;
            async16(&Bs[(wave * 32 + i * 8) * BK],
                    B + (size_t)(n0 + row) * KDIM + k0 + chunk * 8);
        }
        asm volatile("s_waitcnt vmcnt(0)" ::: "memory");
        __syncthreads();

        #pragma unroll
        for (int ks = 0; ks < BK; ks += 32) {
            bf16x8 a[4], b[4];
            #pragma unroll
            for (int mi = 0; mi < 4; ++mi)
                a[mi] = *(const bf16x8*)&As[(wr * 64 + mi * 16 + (lane & 15)) * BK + ks + (lane >> 4) * 8];
            #pragma unroll
            for (int ni = 0; ni < 4; ++ni)
                b[ni] = *(const bf16x8*)&Bs[(wc * 64 + ni * 16 + (lane & 15)) * BK + ks + (lane >> 4) * 8];
            #pragma unroll
            for (int mi = 0; mi < 4; ++mi)
                #pragma unroll
                for (int ni = 0; ni < 4; ++ni)
                    acc[mi][ni] = __builtin_amdgcn_mfma_f32_16x16x32_bf16(a[mi], b[ni], acc[mi][ni], 0, 0, 0);
        }
        __syncthreads();
    }

    // epilogue: + (b_ih + b_hh), store fp32 gates
    #pragma unroll
    for (int mi = 0; mi < 4; ++mi) {
        #pragma unroll
        for (int ni = 0; ni < 4; ++ni) {
            const int col = n0 + wc * 64 + ni * 16 + (lane & 15);
            const float bv = bsum[col];
            #pragma unroll
            for (int r = 0; r < 4; ++r) {
                const int row = m0 + wr * 64 + mi * 16 + (lane >> 4) * 4 + r;
                gates[(size_t)row * GDIM + col] = acc[mi][ni][r] + bv;
            }
        }
    }
}

// ---------------- LSTM cell elementwise ----------------
__global__ void k_cell(const float* __restrict__ gates, float* __restrict__ c,
                       float* __restrict__ h, bf16* __restrict__ Acat) {
    int idx = blockIdx.x * blockDim.x + threadIdx.x;
    if (idx >= NG * DIM) return;
    const int g = idx >> 8, d = idx & (DIM - 1);
    const float* gr = gates + (size_t)g * GDIM;
    const float vi = gr[d];
    const float vf = gr[d + 256];
    const float vg = gr[d + 512];
    const float vo = gr[d + 768];
    const float cn = fast_sigmoid(vf) * c[idx] + fast_sigmoid(vi) * fast_tanh(vg);
    const float hn = fast_sigmoid(vo) * fast_tanh(cn);
    c[idx] = cn;
    h[idx] = hn;
    Acat[(size_t)g * KDIM + DIM + d] = __float2bfloat16(hn);
}

// ---------------- final output: concat([h, readout]) ----------------
__global__ void k_out(const float* __restrict__ h, const float* __restrict__ readout,
                      float* __restrict__ out) {
    int idx = blockIdx.x * blockDim.x + threadIdx.x;
    if (idx >= NG * KDIM) return;
    const int g = idx >> 9, d = idx & (KDIM - 1);
    out[idx] = (d < DIM) ? h[(size_t)g * DIM + d] : readout[(size_t)g * DIM + (d - DIM)];
}

extern "C" void kernel_launch(void* const* d_in, const int* in_sizes, int n_in,
                              void* d_out, int out_size, void* d_ws, size_t ws_size,
                              hipStream_t stream) {
    const float* x     = (const float*)d_in[0];
    const int*   batch = (const int*)d_in[1];
    // d_in[2] = n_graphs scalar (8192, hardcoded)
    const float* Wih   = (const float*)d_in[3];
    const float* Whh   = (const float*)d_in[4];
    const float* bih   = (const float*)d_in[5];
    const float* bhh   = (const float*)d_in[6];
    const int n_nodes  = in_sizes[0] / DIM;
    float* out = (float*)d_out;

    char* ws = (char*)d_ws;
    size_t off = 0;
    auto alloc = [&](size_t bytes) -> void* {
        off = (off + 255) & ~(size_t)255;
        void* p = ws + off;
        off += bytes;
        return p;
    };
    int*   offs    = (int*)  alloc((size_t)(NG + 1) * sizeof(int));
    bf16*  Wcat    = (bf16*) alloc((size_t)GDIM * KDIM * sizeof(bf16));
    float* bsum    = (float*)alloc((size_t)GDIM * sizeof(float));
    bf16*  Acat    = (bf16*) alloc((size_t)NG * KDIM * sizeof(bf16));
    float* h       = (float*)alloc((size_t)NG * DIM * sizeof(float));
    float* c       = (float*)alloc((size_t)NG * DIM * sizeof(float));
    float* readout = (float*)alloc((size_t)NG * DIM * sizeof(float));
    float* gates   = (float*)alloc((size_t)NG * GDIM * sizeof(float));
    (void)ws_size; (void)n_in; (void)out_size;

    k_offsets<<<(n_nodes + 255) / 256, 256, 0, stream>>>(batch, offs, n_nodes);
    k_prep_w<<<(GDIM * KDIM + 255) / 256, 256, 0, stream>>>(Wih, Whh, bih, bhh, Wcat, bsum);
    k_zero<<<(NG * KDIM + 255) / 256, 256, 0, stream>>>(h, c, Acat);

    for (int it = 0; it < N_ITERS; ++it) {
        k_att<<<NG, 256, 0, stream>>>(x, h, offs, readout, Acat);
        k_gemm<<<dim3(NG / BM, GDIM / BN), 256, 0, stream>>>(Acat, Wcat, bsum, gates);
        k_cell<<<(NG * DIM + 255) / 256, 256, 0, stream>>>(gates, c, h, Acat);
    }
    k_out<<<(NG * KDIM + 255) / 256, 256, 0, stream>>>(h, readout, out);
}